// Round 6
// baseline (2541.033 us; speedup 1.0000x reference)
//
#include <hip/hip_runtime.h>

// ModalVerlet: B=16, M=64, T=48000. Producer/consumer wave specialization.
//
// Wave 0 (scan), per step (writing state s, then advancing):
//   r_s  = rcp(e+1)            [e = exp2(z_s) issued in step s-1 -> latency hidden]
//   hs   = fma(phe, fe[s], g2)
//   cz_s = fma(mom2C, z, hs)
//   kl   = fma(m2g2, rA, cz)   [rA = r_{s-1}: lagged z-path, coeff ~1e-8, as R5]
//   W    = fma(CAu, u, z)
//   zn   = fma(CAGB, kl, W)    [z_{s+1}]
//   e    = exp2(zn)            [consumed at top of step s+1]
//   kp   = fma(m2g2, r_s, cz)  [c_s, EXACT r -> strong tanh path unchanged]
//   u'   = fma(Fd, u, kp)      [t = GdF1*u substitution, exact algebra]
// = 8 VALU + 2 trans + (1 ds_write_b128 per 2 steps). p moved to storer:
// p_s = Gd*(u_s + u_{s+1}) (exact: p = t + Gd*c, u' = Fd*u + c).
// fe read via wave-uniform scalar indexing in 16-groups, prefetched one
// 16-step quarter ahead -> s_loads, no vmcnt on this wave.
//
// Wave 1 (storer): per 64-step tile reads (z,u) pairs + boundary u, computes
// q = invC*z and p = Gd*(u+u'), issues 32 global_store_dwordx4 in its slack.

#define NB 16
#define NM 64
#define NT 48000
#define SPI 64
#define NITER (NT / SPI) // 750

__global__ void __launch_bounds__(128, 1) modal_scan_kernel(
    const float* __restrict__ y0,
    const float* __restrict__ omega,
    const float* __restrict__ sigma,
    const float* __restrict__ gamma,
    const float* __restrict__ Phi_e,
    const float* __restrict__ fe_points,
    float* __restrict__ y_out)
{
    const int b   = blockIdx.x;
    const int wid = threadIdx.x >> 6;
    const int m   = threadIdx.x & 63;

    __shared__ float4 lzu[2][SPI / 2][NM]; // (z_t, u_t, z_{t+1}, u_{t+1})
    __shared__ float  lub[2][NM];          // boundary u_{64(j+1)}

    const float k    = 1.0f / 48000.0f;
    const float k2   = 0.5f * k;
    const float invC = 0.34657359027997264f; // ln(2)/2

    if (wid == 0) {
        // ---------------- scan wave ----------------
        const float om  = omega[b * NM + m];
        const float sg  = sigma[b * NM + m];
        const float g   = gamma[b];
        const float phe = Phi_e[b * NM + m];
        const float om2 = om * om;
        const float g2  = g * g;

        const float E    = 1.0f - k * sg;
        const float dinv = 1.0f / (1.0f + k * sg);
        const float A    = k * E;
        const float Bc   = k * k2;
        const float Fd   = E * dinv;
        const float Gd   = k2 * dinv;
        const float AGB  = A * Gd + Bc;
        const float m2g2 = -2.0f * g2;

        const float C    = 2.885390081777927f;   // 2*log2(e)
        const float CA   = C * A;
        const float CAGB = C * AGB;
        const float mom2C = -om2 * invC;
        const float GdF1 = Gd * (1.0f + Fd);
        const float CAu  = CA * GdF1;

        const float q0v = y0[b * 2 * NM + m];
        const float p0v = y0[b * 2 * NM + NM + m];

        const float* fe_row = fe_points + (size_t)b * NT; // wave-uniform reads

        float sfeA[16], sfeB[16];
#pragma unroll
        for (int i = 0; i < 16; ++i) sfeA[i] = fe_row[i];

        // ---- preamble: state 0 ----
        float z  = C * q0v;
        float e  = __builtin_amdgcn_exp2f(z);
        float rA = __builtin_amdgcn_rcpf(e + 1.0f);      // r_0 (lag slot at s=0)
        {
            float hs0 = fmaf(phe, sfeA[0], g2);
            float cz0 = fmaf(mom2C, z, hs0);
            float c0  = fmaf(m2g2, rA, cz0);
            float t0  = fmaf(-Gd, c0, p0v);              // p_0 = t_0 + Gd*c_0
            float u0  = t0 / GdF1;
            // carried u:
            // (declared below to keep scope clean)
            (void)u0;
        }
        float hs0 = fmaf(phe, sfeA[0], g2);
        float cz0 = fmaf(mom2C, z, hs0);
        float c0  = fmaf(m2g2, rA, cz0);
        float u   = fmaf(-Gd, c0, p0v) / GdF1;           // u_0

#define STEP(FE) {                                        \
    float rnew = __builtin_amdgcn_rcpf(e + 1.0f);         \
    float hs = fmaf(phe, (FE), g2);                       \
    float cz = fmaf(mom2C, z, hs);                        \
    float kl = fmaf(m2g2, rA, cz);        /* lagged r  */ \
    float W  = fmaf(CAu, u, z);                           \
    float zn = fmaf(CAGB, kl, W);         /* z_{s+1}   */ \
    e = __builtin_amdgcn_exp2f(zn);                       \
    float kp = fmaf(m2g2, rnew, cz);      /* c_s exact */ \
    float un = fmaf(Fd, u, kp);           /* u_{s+1}   */ \
    rA = rnew; z = zn; u = un; }

#define STEP2(F0, F1, SL, TP) {                           \
    float za = z, ua = u; STEP(F0);                       \
    float zb = z, ubv = u; STEP(F1);                      \
    lzu[SL][TP][m] = make_float4(za, ua, zb, ubv); }

#define Q16(BUF, SL, TPB) \
    STEP2(BUF[0],  BUF[1],  SL, (TPB) + 0); \
    STEP2(BUF[2],  BUF[3],  SL, (TPB) + 1); \
    STEP2(BUF[4],  BUF[5],  SL, (TPB) + 2); \
    STEP2(BUF[6],  BUF[7],  SL, (TPB) + 3); \
    STEP2(BUF[8],  BUF[9],  SL, (TPB) + 4); \
    STEP2(BUF[10], BUF[11], SL, (TPB) + 5); \
    STEP2(BUF[12], BUF[13], SL, (TPB) + 6); \
    STEP2(BUF[14], BUF[15], SL, (TPB) + 7);

        for (int j = 0; j < NITER; ++j) {
            const int base = SPI * j;
            const int sl = j & 1;

            // Q0: prefetch B <- base+16, consume A (fe[base..base+15])
#pragma unroll
            for (int i = 0; i < 16; ++i) sfeB[i] = fe_row[base + 16 + i];
            if (sl == 0) { Q16(sfeA, 0, 0); } else { Q16(sfeA, 1, 0); }

            // Q1: prefetch A <- base+32, consume B
#pragma unroll
            for (int i = 0; i < 16; ++i) sfeA[i] = fe_row[base + 32 + i];
            if (sl == 0) { Q16(sfeB, 0, 8); } else { Q16(sfeB, 1, 8); }

            // Q2: prefetch B <- base+48, consume A
#pragma unroll
            for (int i = 0; i < 16; ++i) sfeB[i] = fe_row[base + 48 + i];
            if (sl == 0) { Q16(sfeA, 0, 16); } else { Q16(sfeA, 1, 16); }

            // Q3: prefetch A <- base+64 (clamped), consume B
            const int nb = (base + 64 <= NT - 16) ? (base + 64) : (NT - 16);
#pragma unroll
            for (int i = 0; i < 16; ++i) sfeA[i] = fe_row[nb + i];
            if (sl == 0) { Q16(sfeB, 0, 24); } else { Q16(sfeB, 1, 24); }

            lub[sl][m] = u;   // boundary u_{64(j+1)}
            __syncthreads();
        }
#undef Q16
#undef STEP2
#undef STEP
    } else {
        // ---------------- storer wave ----------------
        const float sg   = sigma[b * NM + m];
        const float dinv = 1.0f / (1.0f + k * sg);
        const float Gd   = k2 * dinv;

        float* yql = y_out + ((size_t)b * 2 * NM + m) * (size_t)NT;
        float* ypl = yql + (size_t)NM * NT;

        for (int j = 0; j < NITER; ++j) {
            __syncthreads();
            const int sl = j & 1;

            float4* dq = reinterpret_cast<float4*>(yql + (size_t)SPI * j);
            float4* dp = reinterpret_cast<float4*>(ypl + (size_t)SPI * j);

#pragma unroll
            for (int i = 0; i < 16; ++i) {
                float4 va = lzu[sl][2 * i][m];
                float4 vb = lzu[sl][2 * i + 1][m];
                float  u2 = (i < 15) ? lzu[sl][2 * i + 2][m].y : lub[sl][m];
                dq[i] = make_float4(invC * va.x, invC * va.z,
                                    invC * vb.x, invC * vb.z);
                dp[i] = make_float4(Gd * (va.y + va.w), Gd * (va.w + vb.y),
                                    Gd * (vb.y + vb.w), Gd * (vb.w + u2));
            }
        }
    }
}

// w[b,t] = sum_m Phi_o[b,m] * y[b,m,t]  (fully parallel, memory/L3-bound)
__global__ void __launch_bounds__(256) w_kernel(
    const float* __restrict__ y,
    const float* __restrict__ Phi_o,
    float* __restrict__ w)
{
    const int b  = blockIdx.y;
    const int t4 = blockIdx.x * 256 + threadIdx.x;
    if (t4 >= NT / 4) return;

    const float4* yb = reinterpret_cast<const float4*>(y + (size_t)b * 2 * NM * NT);
    const float*  po = Phi_o + b * NM;

    float4 acc = make_float4(0.f, 0.f, 0.f, 0.f);
    #pragma unroll 8
    for (int mm = 0; mm < NM; ++mm) {
        float  c = po[mm];
        float4 v = yb[mm * (NT / 4) + t4];
        acc.x = fmaf(c, v.x, acc.x);
        acc.y = fmaf(c, v.y, acc.y);
        acc.z = fmaf(c, v.z, acc.z);
        acc.w = fmaf(c, v.w, acc.w);
    }
    reinterpret_cast<float4*>(w + (size_t)b * NT)[t4] = acc;
}

extern "C" void kernel_launch(void* const* d_in, const int* in_sizes, int n_in,
                              void* d_out, int out_size, void* d_ws, size_t ws_size,
                              hipStream_t stream)
{
    // inputs: 0=fs, 1=num_samples, 2=y0, 3=omega, 4=sigma, 5=gamma,
    //         6=Phi_e, 7=Phi_o, 8=fe_points
    const float* y0    = (const float*)d_in[2];
    const float* omega = (const float*)d_in[3];
    const float* sigma = (const float*)d_in[4];
    const float* gamma = (const float*)d_in[5];
    const float* Phi_e = (const float*)d_in[6];
    const float* Phi_o = (const float*)d_in[7];
    const float* fe    = (const float*)d_in[8];

    float* y_out = (float*)d_out;                    // (B, 2M, T)
    float* w_out = y_out + (size_t)NB * 2 * NM * NT; // (B, T)

    modal_scan_kernel<<<NB, 128, 0, stream>>>(y0, omega, sigma, gamma, Phi_e, fe, y_out);

    dim3 grid((NT / 4 + 255) / 256, NB);
    w_kernel<<<grid, 256, 0, stream>>>(y_out, Phi_o, w_out);
}

// Round 7
// 1475.981 us; speedup vs baseline: 1.7216x; 1.7216x over previous
//
#include <hip/hip_runtime.h>

// ModalVerlet: B=16, M=64, T=48000. Producer/consumer wave specialization.
//
// Wave 0 (scan), step s (7 VALU + 2 trans, all trans latency pipelined away):
//   rNew = rcp(aPrev)        // r_{s-1}; aPrev = exp2(z_{s-1})+1 from step s-1
//   hs   = fma(phe, fe[s], g2)
//   cz   = fma(mom2C, z, hs)
//   kl   = fma(m2g2, rU, cz) // c~_s with r lagged 2 steps (error ~1e-9/step,
//                            // damped; far below fp32 drift of the scheme)
//   W    = fma(CAu, u, z)
//   zn   = fma(CAGB, kl, W)  // z_{s+1}
//   un   = fma(Fd, u, kl)    // u_{s+1}   [t = GdF1*u substitution, exact]
//   e    = exp2(zn)          // consumed (+1) next step, rcp the step after
//   aNew = ePrev + 1
// Loop-carried chain: cz -> kl -> zn (3 fmas). p reconstruction moved to the
// storer wave: p_s = Gd*(u_s + u_{s+1}) (exact algebra).
// fe: per-lane float4 double-buffer (R5-proven; R6's scalar-indexed uniform
// loads regressed 1.7x - 16 global_load_dwords/quarter + vmcnt in-stream).
//
// Wave 1 (storer): per 32-step tile reads (z,u,z,u) float4s + boundary u,
// computes q = invC*z, p = Gd*(u+u'), issues 16 global_store_dwordx4 in slack.

#define NB 16
#define NM 64
#define NT 48000
#define SPI 32
#define NITER (NT / SPI) // 1500

__global__ void __launch_bounds__(128, 1) modal_scan_kernel(
    const float* __restrict__ y0,
    const float* __restrict__ omega,
    const float* __restrict__ sigma,
    const float* __restrict__ gamma,
    const float* __restrict__ Phi_e,
    const float* __restrict__ fe_points,
    float* __restrict__ y_out)
{
    const int b   = blockIdx.x;
    const int wid = threadIdx.x >> 6;
    const int m   = threadIdx.x & 63;

    __shared__ float4 lzu[2][SPI / 2][NM]; // (z_t, u_t, z_{t+1}, u_{t+1})
    __shared__ float  lub[2][NM];          // boundary u at tile end

    const float k    = 1.0f / 48000.0f;
    const float k2   = 0.5f * k;
    const float invC = 0.34657359027997264f; // ln(2)/2

    if (wid == 0) {
        // ---------------- scan wave ----------------
        const float om  = omega[b * NM + m];
        const float sg  = sigma[b * NM + m];
        const float g   = gamma[b];
        const float phe = Phi_e[b * NM + m];
        const float om2 = om * om;
        const float g2  = g * g;

        const float E    = 1.0f - k * sg;
        const float dinv = 1.0f / (1.0f + k * sg);
        const float A    = k * E;
        const float Bc   = k * k2;
        const float Fd   = E * dinv;
        const float Gd   = k2 * dinv;
        const float AGB  = A * Gd + Bc;
        const float m2g2 = -2.0f * g2;

        const float C    = 2.885390081777927f;   // 2*log2(e)
        const float CA   = C * A;
        const float CAGB = C * AGB;
        const float mom2C = -om2 * invC;
        const float GdF1 = Gd * (1.0f + Fd);
        const float CAu  = CA * GdF1;

        const float q0v = y0[b * 2 * NM + m];
        const float p0v = y0[b * 2 * NM + NM + m];

        const float4* fe4 = reinterpret_cast<const float4*>(fe_points + (size_t)b * NT);

        float4 bufA[8], bufB[8];
#pragma unroll
        for (int i = 0; i < 8; ++i) bufA[i] = fe4[i];
#pragma unroll
        for (int i = 0; i < 8; ++i) bufB[i] = fe4[8 + i];

        // ---- preamble: state 0 + pipeline priming ----
        float z  = C * q0v;
        float e0 = __builtin_amdgcn_exp2f(z);
        float a0 = e0 + 1.0f;
        float r0 = __builtin_amdgcn_rcpf(a0);
        float u;
        {
            float hs0 = fmaf(phe, bufA[0].x, g2);
            float cz0 = fmaf(mom2C, z, hs0);
            float c0  = fmaf(m2g2, r0, cz0);
            u = fmaf(-Gd, c0, p0v) / GdF1;   // u_0 : p_0 = Gd*(u_0+u_1)
        }
        float rU = r0, aPrev = a0, ePrev = e0;

#define STEP(FE) {                                        \
    float rNew = __builtin_amdgcn_rcpf(aPrev);            \
    float hs = fmaf(phe, (FE), g2);                       \
    float cz = fmaf(mom2C, z, hs);                        \
    float kl = fmaf(m2g2, rU, cz);                        \
    float W  = fmaf(CAu, u, z);                           \
    float zn = fmaf(CAGB, kl, W);                         \
    float un = fmaf(Fd, u, kl);                           \
    float e  = __builtin_amdgcn_exp2f(zn);                \
    aPrev = ePrev + 1.0f;                                 \
    ePrev = e; rU = rNew; z = zn; u = un; }

#define STEP2(F0, F1, SL, TP) {                           \
    float za = z, ua = u; STEP(F0);                       \
    float zb = z, ub_ = u; STEP(F1);                      \
    lzu[SL][TP][m] = make_float4(za, ua, zb, ub_); }

#define STEP32(SL, BUF) \
    STEP2(BUF[0].x, BUF[0].y, SL, 0);  STEP2(BUF[0].z, BUF[0].w, SL, 1);  \
    STEP2(BUF[1].x, BUF[1].y, SL, 2);  STEP2(BUF[1].z, BUF[1].w, SL, 3);  \
    STEP2(BUF[2].x, BUF[2].y, SL, 4);  STEP2(BUF[2].z, BUF[2].w, SL, 5);  \
    STEP2(BUF[3].x, BUF[3].y, SL, 6);  STEP2(BUF[3].z, BUF[3].w, SL, 7);  \
    STEP2(BUF[4].x, BUF[4].y, SL, 8);  STEP2(BUF[4].z, BUF[4].w, SL, 9);  \
    STEP2(BUF[5].x, BUF[5].y, SL, 10); STEP2(BUF[5].z, BUF[5].w, SL, 11); \
    STEP2(BUF[6].x, BUF[6].y, SL, 12); STEP2(BUF[6].z, BUF[6].w, SL, 13); \
    STEP2(BUF[7].x, BUF[7].y, SL, 14); STEP2(BUF[7].z, BUF[7].w, SL, 15);

        // j-loop unrolled by 2: even iters consume bufA (slot 0), odd bufB
        // (slot 1); each buffer refilled right after consumption.
        for (int j = 0; j < NITER; j += 2) {
            STEP32(0, bufA);
            lub[0][m] = u;
            {
                const int jn = (j + 2 < NITER) ? (j + 2) : j;
#pragma unroll
                for (int i = 0; i < 8; ++i) bufA[i] = fe4[8 * jn + i];
            }
            __syncthreads();

            STEP32(1, bufB);
            lub[1][m] = u;
            {
                const int jn = (j + 3 < NITER) ? (j + 3) : (j + 1);
#pragma unroll
                for (int i = 0; i < 8; ++i) bufB[i] = fe4[8 * jn + i];
            }
            __syncthreads();
        }
#undef STEP32
#undef STEP2
#undef STEP
    } else {
        // ---------------- storer wave ----------------
        const float sg   = sigma[b * NM + m];
        const float dinv = 1.0f / (1.0f + k * sg);
        const float Gd   = k2 * dinv;

        float* yql = y_out + ((size_t)b * 2 * NM + m) * (size_t)NT;
        float* ypl = yql + (size_t)NM * NT;

        for (int j = 0; j < NITER; ++j) {
            __syncthreads();
            const int sl = j & 1;

            float4* dq = reinterpret_cast<float4*>(yql + (size_t)SPI * j);
            float4* dp = reinterpret_cast<float4*>(ypl + (size_t)SPI * j);

#pragma unroll
            for (int i = 0; i < 8; ++i) {
                float4 va = lzu[sl][2 * i][m];
                float4 vb = lzu[sl][2 * i + 1][m];
                float  u2 = (i < 7) ? lzu[sl][2 * i + 2][m].y : lub[sl][m];
                dq[i] = make_float4(invC * va.x, invC * va.z,
                                    invC * vb.x, invC * vb.z);
                dp[i] = make_float4(Gd * (va.y + va.w), Gd * (va.w + vb.y),
                                    Gd * (vb.y + vb.w), Gd * (vb.w + u2));
            }
        }
    }
}

// w[b,t] = sum_m Phi_o[b,m] * y[b,m,t]  (fully parallel, memory/L3-bound)
__global__ void __launch_bounds__(256) w_kernel(
    const float* __restrict__ y,
    const float* __restrict__ Phi_o,
    float* __restrict__ w)
{
    const int b  = blockIdx.y;
    const int t4 = blockIdx.x * 256 + threadIdx.x;
    if (t4 >= NT / 4) return;

    const float4* yb = reinterpret_cast<const float4*>(y + (size_t)b * 2 * NM * NT);
    const float*  po = Phi_o + b * NM;

    float4 acc = make_float4(0.f, 0.f, 0.f, 0.f);
    #pragma unroll 8
    for (int mm = 0; mm < NM; ++mm) {
        float  c = po[mm];
        float4 v = yb[mm * (NT / 4) + t4];
        acc.x = fmaf(c, v.x, acc.x);
        acc.y = fmaf(c, v.y, acc.y);
        acc.z = fmaf(c, v.z, acc.z);
        acc.w = fmaf(c, v.w, acc.w);
    }
    reinterpret_cast<float4*>(w + (size_t)b * NT)[t4] = acc;
}

extern "C" void kernel_launch(void* const* d_in, const int* in_sizes, int n_in,
                              void* d_out, int out_size, void* d_ws, size_t ws_size,
                              hipStream_t stream)
{
    // inputs: 0=fs, 1=num_samples, 2=y0, 3=omega, 4=sigma, 5=gamma,
    //         6=Phi_e, 7=Phi_o, 8=fe_points
    const float* y0    = (const float*)d_in[2];
    const float* omega = (const float*)d_in[3];
    const float* sigma = (const float*)d_in[4];
    const float* gamma = (const float*)d_in[5];
    const float* Phi_e = (const float*)d_in[6];
    const float* Phi_o = (const float*)d_in[7];
    const float* fe    = (const float*)d_in[8];

    float* y_out = (float*)d_out;                    // (B, 2M, T)
    float* w_out = y_out + (size_t)NB * 2 * NM * NT; // (B, T)

    modal_scan_kernel<<<NB, 128, 0, stream>>>(y0, omega, sigma, gamma, Phi_e, fe, y_out);

    dim3 grid((NT / 4 + 255) / 256, NB);
    w_kernel<<<grid, 256, 0, stream>>>(y_out, Phi_o, w_out);
}

// Round 8
// 1447.760 us; speedup vs baseline: 1.7551x; 1.0195x over previous
//
#include <hip/hip_runtime.h>

// ModalVerlet: B=16, M=64, T=48000. 3-wave specialization: 1 scan + 2 storers.
//
// Wave 0 (scan) — identical math to R7 (absmax 2.0): step s =
//   rNew=rcp(aPrev); hs=fma(phe,fe,g2); cz=fma(mom2C,z,hs); kl=fma(m2g2,rU,cz);
//   W=fma(CAu,u,z); zn=fma(CAGB,kl,W); un=fma(Fd,u,kl); e=exp2(zn); a=ePrev+1.
//   7 VALU + 2 trans, 3-fma loop chain, trans latency fully pipelined.
//   Writes (z,u) pairs to a 4-slot LDS ring (1 ds_write_b128 / 2 steps).
//
// Waves 1,2 (storers) — R5-R7 had ONE storer doing 16 global_store_dwordx4
// per barrier interval; store-data VGPR reuse within < store-ack latency
// (~300-500cyc) serializes on s_waitcnt vmcnt -> flat ~2330 cyc/tile floor
// regardless of scan work (R5->R7: -17% scan issue, -2.5% time). Now each
// storer owns alternate tiles and splits its tile across TWO intervals
// (phase A: dq/dp[0..3] in interval j, phase B: [4..7] in interval j+1);
// the 4-slot ring keeps data live. Per-interval per-wave duty halves and
// store-acks overlap across two independent waves.
//
// p_s = Gd*(u_s + u_{s+1}) (exact); boundary u for the last float4 of a tile
// comes from the NEXT tile's first LDS entry (published exactly in time);
// final u_48000 via a pseudo-entry + one extra barrier.

#define NB 16
#define NM 64
#define NT 48000
#define SPI 32
#define NITER (NT / SPI) // 1500
#define NSLOT 4

__global__ void __launch_bounds__(192, 1) modal_scan_kernel(
    const float* __restrict__ y0,
    const float* __restrict__ omega,
    const float* __restrict__ sigma,
    const float* __restrict__ gamma,
    const float* __restrict__ Phi_e,
    const float* __restrict__ fe_points,
    float* __restrict__ y_out)
{
    const int b   = blockIdx.x;
    const int wid = threadIdx.x >> 6;
    const int m   = threadIdx.x & 63;

    __shared__ float4 lzu[NSLOT][SPI / 2][NM]; // (z_t,u_t,z_{t+1},u_{t+1}) ; 64 KB

    const float k    = 1.0f / 48000.0f;
    const float k2   = 0.5f * k;
    const float invC = 0.34657359027997264f; // ln(2)/2

    if (wid == 0) {
        // ---------------- scan wave ----------------
        const float om  = omega[b * NM + m];
        const float sg  = sigma[b * NM + m];
        const float g   = gamma[b];
        const float phe = Phi_e[b * NM + m];
        const float om2 = om * om;
        const float g2  = g * g;

        const float E    = 1.0f - k * sg;
        const float dinv = 1.0f / (1.0f + k * sg);
        const float A    = k * E;
        const float Bc   = k * k2;
        const float Fd   = E * dinv;
        const float Gd   = k2 * dinv;
        const float AGB  = A * Gd + Bc;
        const float m2g2 = -2.0f * g2;

        const float C    = 2.885390081777927f;   // 2*log2(e)
        const float CA   = C * A;
        const float CAGB = C * AGB;
        const float mom2C = -om2 * invC;
        const float GdF1 = Gd * (1.0f + Fd);
        const float CAu  = CA * GdF1;

        const float q0v = y0[b * 2 * NM + m];
        const float p0v = y0[b * 2 * NM + NM + m];

        const float4* fe4 = reinterpret_cast<const float4*>(fe_points + (size_t)b * NT);

        float4 bufA[8], bufB[8];
#pragma unroll
        for (int i = 0; i < 8; ++i) bufA[i] = fe4[i];
#pragma unroll
        for (int i = 0; i < 8; ++i) bufB[i] = fe4[8 + i];

        // ---- preamble: state 0 + trans pipeline priming ----
        float z  = C * q0v;
        float e0 = __builtin_amdgcn_exp2f(z);
        float a0 = e0 + 1.0f;
        float r0 = __builtin_amdgcn_rcpf(a0);
        float u;
        {
            float hs0 = fmaf(phe, bufA[0].x, g2);
            float cz0 = fmaf(mom2C, z, hs0);
            float c0  = fmaf(m2g2, r0, cz0);
            u = fmaf(-Gd, c0, p0v) / GdF1;   // u_0 : p_0 = Gd*(u_0+u_1)
        }
        float rU = r0, aPrev = a0, ePrev = e0;

#define STEP(FE) {                                        \
    float rNew = __builtin_amdgcn_rcpf(aPrev);            \
    float hs = fmaf(phe, (FE), g2);                       \
    float cz = fmaf(mom2C, z, hs);                        \
    float kl = fmaf(m2g2, rU, cz);                        \
    float W  = fmaf(CAu, u, z);                           \
    float zn = fmaf(CAGB, kl, W);                         \
    float un = fmaf(Fd, u, kl);                           \
    float e  = __builtin_amdgcn_exp2f(zn);                \
    aPrev = ePrev + 1.0f;                                 \
    ePrev = e; rU = rNew; z = zn; u = un; }

#define STEP2(F0, F1, SP, TP) {                           \
    float za = z, ua = u; STEP(F0);                       \
    float zb = z, ub_ = u; STEP(F1);                      \
    (SP)[(TP) * NM] = make_float4(za, ua, zb, ub_); }

#define STEP32(SP, BUF) \
    STEP2(BUF[0].x, BUF[0].y, SP, 0);  STEP2(BUF[0].z, BUF[0].w, SP, 1);  \
    STEP2(BUF[1].x, BUF[1].y, SP, 2);  STEP2(BUF[1].z, BUF[1].w, SP, 3);  \
    STEP2(BUF[2].x, BUF[2].y, SP, 4);  STEP2(BUF[2].z, BUF[2].w, SP, 5);  \
    STEP2(BUF[3].x, BUF[3].y, SP, 6);  STEP2(BUF[3].z, BUF[3].w, SP, 7);  \
    STEP2(BUF[4].x, BUF[4].y, SP, 8);  STEP2(BUF[4].z, BUF[4].w, SP, 9);  \
    STEP2(BUF[5].x, BUF[5].y, SP, 10); STEP2(BUF[5].z, BUF[5].w, SP, 11); \
    STEP2(BUF[6].x, BUF[6].y, SP, 12); STEP2(BUF[6].z, BUF[6].w, SP, 13); \
    STEP2(BUF[7].x, BUF[7].y, SP, 14); STEP2(BUF[7].z, BUF[7].w, SP, 15);

        for (int j = 0; j < NITER; j += 2) {
            float4* s0 = &lzu[j & 3][0][m];
            STEP32(s0, bufA);
            {
                const int jn = (j + 2 < NITER) ? (j + 2) : j;
#pragma unroll
                for (int i = 0; i < 8; ++i) bufA[i] = fe4[8 * jn + i];
            }
            __syncthreads();

            float4* s1 = &lzu[(j + 1) & 3][0][m];
            STEP32(s1, bufB);
            {
                const int jn = (j + 3 < NITER) ? (j + 3) : (j + 1);
#pragma unroll
                for (int i = 0; i < 8; ++i) bufB[i] = fe4[8 * jn + i];
            }
            __syncthreads();
        }
        // pseudo-entry for u_{NT}: slot NITER&3 == 0, entry 0, .y = final u
        lzu[NITER & 3][0][m] = make_float4(0.0f, u, 0.0f, 0.0f);
        __syncthreads();   // barrier #NITER+1 (matched by storers)
#undef STEP32
#undef STEP2
#undef STEP
    } else {
        // ---------------- storer waves (w = 0,1) ----------------
        const int w = wid - 1;
        const float sg   = sigma[b * NM + m];
        const float dinv = 1.0f / (1.0f + k * sg);
        const float Gd   = k2 * dinv;

        float* yql = y_out + ((size_t)b * 2 * NM + m) * (size_t)NT;
        float* ypl = yql + (size_t)NM * NT;

        // HALF(tile, half): write dq/dp float4s [half*4 .. half*4+3] of `tile`.
        // u boundary for i==7 comes from tile+1's entry 0 (.y), valid because
        // tile+1 is published by the time phase B runs (interval tile+1).
        auto HALF = [&](int tile, int half) {
            const float4* sp  = &lzu[tile & 3][0][m];
            const float4* spn = &lzu[(tile + 1) & 3][0][m];
            float4* dq = reinterpret_cast<float4*>(yql + (size_t)SPI * tile) + half * 4;
            float4* dp = reinterpret_cast<float4*>(ypl + (size_t)SPI * tile) + half * 4;
#pragma unroll
            for (int i = half * 4; i < half * 4 + 4; ++i) {
                float4 va = sp[(2 * i) * NM];
                float4 vb = sp[(2 * i + 1) * NM];
                float  u2 = (i < 7) ? sp[(2 * i + 2) * NM].y : spn[0].y;
                dq[i - half * 4] = make_float4(invC * va.x, invC * va.z,
                                               invC * vb.x, invC * vb.z);
                dp[i - half * 4] = make_float4(Gd * (va.y + va.w), Gd * (va.w + vb.y),
                                               Gd * (vb.y + vb.w), Gd * (vb.w + u2));
            }
        };

        for (int j = 0; j < NITER; ++j) {
            __syncthreads();           // publishes tile j
            if ((j & 1) == w) {
                HALF(j, 0);            // phase A of my tile j
            } else if (j >= 1) {
                HALF(j - 1, 1);        // phase B of my tile j-1 (needs tile j's u)
            }
        }
        __syncthreads();               // publishes pseudo-entry (u_NT)
        if (((NITER - 1) & 1) == w) {
            HALF(NITER - 1, 1);        // phase B of the final tile
        }
    }
}

// w[b,t] = sum_m Phi_o[b,m] * y[b,m,t]  (fully parallel, memory/L3-bound)
__global__ void __launch_bounds__(256) w_kernel(
    const float* __restrict__ y,
    const float* __restrict__ Phi_o,
    float* __restrict__ w)
{
    const int b  = blockIdx.y;
    const int t4 = blockIdx.x * 256 + threadIdx.x;
    if (t4 >= NT / 4) return;

    const float4* yb = reinterpret_cast<const float4*>(y + (size_t)b * 2 * NM * NT);
    const float*  po = Phi_o + b * NM;

    float4 acc = make_float4(0.f, 0.f, 0.f, 0.f);
    #pragma unroll 8
    for (int mm = 0; mm < NM; ++mm) {
        float  c = po[mm];
        float4 v = yb[mm * (NT / 4) + t4];
        acc.x = fmaf(c, v.x, acc.x);
        acc.y = fmaf(c, v.y, acc.y);
        acc.z = fmaf(c, v.z, acc.z);
        acc.w = fmaf(c, v.w, acc.w);
    }
    reinterpret_cast<float4*>(w + (size_t)b * NT)[t4] = acc;
}

extern "C" void kernel_launch(void* const* d_in, const int* in_sizes, int n_in,
                              void* d_out, int out_size, void* d_ws, size_t ws_size,
                              hipStream_t stream)
{
    // inputs: 0=fs, 1=num_samples, 2=y0, 3=omega, 4=sigma, 5=gamma,
    //         6=Phi_e, 7=Phi_o, 8=fe_points
    const float* y0    = (const float*)d_in[2];
    const float* omega = (const float*)d_in[3];
    const float* sigma = (const float*)d_in[4];
    const float* gamma = (const float*)d_in[5];
    const float* Phi_e = (const float*)d_in[6];
    const float* Phi_o = (const float*)d_in[7];
    const float* fe    = (const float*)d_in[8];

    float* y_out = (float*)d_out;                    // (B, 2M, T)
    float* w_out = y_out + (size_t)NB * 2 * NM * NT; // (B, T)

    modal_scan_kernel<<<NB, 192, 0, stream>>>(y0, omega, sigma, gamma, Phi_e, fe, y_out);

    dim3 grid((NT / 4 + 255) / 256, NB);
    w_kernel<<<grid, 256, 0, stream>>>(y_out, Phi_o, w_out);
}